// Round 4
// baseline (265.572 us; speedup 1.0000x reference)
//
#include <hip/hip_runtime.h>

#define Bsz 128
#define Tsz 256
#define Nsz 128
#define Asz 512
#define Vsz 512
#define LIN_BLOCKS 12288

typedef __attribute__((ext_vector_type(8))) short bh8;
typedef __attribute__((ext_vector_type(4))) float f32x4;

__device__ __forceinline__ unsigned short f2bf(float x) {
  unsigned int u = __float_as_uint(x);
  return (unsigned short)((u + 0x7fffu + ((u >> 16) & 1u)) >> 16);
}
__device__ __forceinline__ float bf2f(unsigned short h) {
  return __uint_as_float(((unsigned int)h) << 16);
}
__device__ __forceinline__ float fast_tanh(float x) {
  float ax = fabsf(x);
  float e = __expf(-2.f * ax);
  float t = (1.f - e) / (1.f + e);
  return copysignf(t, x);
}

// async global->LDS, 16B per lane; LDS dest must be wave-uniform base.
__device__ __forceinline__ void gld16(const void* g, void* l) {
  __builtin_amdgcn_global_load_lds(
      (const __attribute__((address_space(1))) unsigned int*)g,
      (__attribute__((address_space(3))) unsigned int*)l, 16, 0, 0);
}

// load 8 consecutive f32, split into hi/lo bf16 fragments (truncation split:
// hi = top16(x); lo = top16(x - hi). 3-term MFMA coverage ~2^-15 rel.)
struct Frag2 { bh8 hi, lo; };
__device__ __forceinline__ Frag2 load_split8(const float* p) {
  float4 x0 = *(const float4*)p;
  float4 x1 = *(const float4*)(p + 4);
  float xs[8] = {x0.x, x0.y, x0.z, x0.w, x1.x, x1.y, x1.z, x1.w};
  union { unsigned int u[4]; bh8 v; } H, L;
#pragma unroll
  for (int i = 0; i < 4; ++i) {
    unsigned int a = __float_as_uint(xs[2 * i]);
    unsigned int b = __float_as_uint(xs[2 * i + 1]);
    H.u[i] = (a >> 16) | (b & 0xffff0000u);
    float la = xs[2 * i]     - __uint_as_float(a & 0xffff0000u);
    float lb = xs[2 * i + 1] - __uint_as_float(b & 0xffff0000u);
    L.u[i] = (__float_as_uint(la) >> 16) | (__float_as_uint(lb) & 0xffff0000u);
  }
  Frag2 r; r.hi = H.v; r.lo = L.v; return r;
}

// lin_a/lin_b (one wave per row) + W^T -> hi/lo bf16 (converted ONCE)
__global__ __launch_bounds__(256) void prep(
    const float* __restrict__ AO, const float* __restrict__ inputs,
    const float* __restrict__ W, const float* __restrict__ a_w,
    const float* __restrict__ b_w, float* __restrict__ lin_a,
    float* __restrict__ lin_b, unsigned short* __restrict__ WT_hi,
    unsigned short* __restrict__ WT_lo)
{
  __shared__ float t[64][65];
  int tid = threadIdx.x;
  if (blockIdx.x < LIN_BLOCKS) {
    int gw = (blockIdx.x * 256 + tid) >> 6;
    int lane = tid & 63;
    const float* src; const float* w; float* dst;
    if (gw < Bsz * Nsz) { src = AO + (long)gw * Asz; w = a_w; dst = lin_a + gw; }
    else { int r = gw - Bsz * Nsz; src = inputs + (long)r * Vsz; w = b_w; dst = lin_b + r; }
    float4 x0 = *(const float4*)(src + lane * 4);
    float4 x1 = *(const float4*)(src + 256 + lane * 4);
    float4 w0 = *(const float4*)(w + lane * 4);
    float4 w1 = *(const float4*)(w + 256 + lane * 4);
    float d = x0.x*w0.x + x0.y*w0.y + x0.z*w0.z + x0.w*w0.w
            + x1.x*w1.x + x1.y*w1.y + x1.z*w1.z + x1.w*w1.w;
#pragma unroll
    for (int off = 32; off; off >>= 1) d += __shfl_xor(d, off);
    if (lane == 0) *dst = d;
  } else {
    int bb = blockIdx.x - LIN_BLOCKS;
    int a0 = (bb & 7) * 64, v0 = (bb >> 3) * 64;
#pragma unroll
    for (int l = 0; l < 4; ++l) {
      int idx = tid + l * 256;
      int r = idx >> 4, c = (idx & 15) * 4;
      float4 v = *(const float4*)(W + (long)(a0 + r) * Vsz + v0 + c);
      t[r][c] = v.x; t[r][c+1] = v.y; t[r][c+2] = v.z; t[r][c+3] = v.w;
    }
    __syncthreads();
#pragma unroll
    for (int l = 0; l < 4; ++l) {
      int idx = tid + l * 256;
      int r = idx >> 4, c = (idx & 15) * 4;   // r = v-local, c = a-local
      ushort4 h, lo;
      unsigned short* hp = (unsigned short*)&h;
      unsigned short* lp = (unsigned short*)&lo;
#pragma unroll
      for (int j = 0; j < 4; ++j) {
        float x = t[c + j][r];
        hp[j] = f2bf(x);
        lp[j] = f2bf(x - bf2f(hp[j]));
      }
      *(ushort4*)&WT_hi[(long)(v0 + r) * Asz + a0 + c] = h;
      *(ushort4*)&WT_lo[(long)(v0 + r) * Asz + a0 + c] = lo;
    }
  }
}

// aM = AO @ W, 3-term split. A: direct-to-reg f32 split. B: global_load_lds
// from pre-converted WT. Out: aM_hi/aM_lo bf16.
__global__ __launch_bounds__(256) void gemm_aM(
    const float* __restrict__ AO, const unsigned short* __restrict__ WT_hi,
    const unsigned short* __restrict__ WT_lo,
    unsigned short* __restrict__ aM_hi, unsigned short* __restrict__ aM_lo)
{
  __shared__ unsigned short b_hi[128][32];
  __shared__ unsigned short b_lo[128][32];
  int tid = threadIdx.x;
  int wave = tid >> 6, lane = tid & 63;
  int wr = wave >> 1, wc = wave & 1;
  int lr = lane & 15, kg = lane >> 4;
  long m0 = (long)blockIdx.x * 128;   // over 16384 rows
  int  n0 = blockIdx.y * 128;         // over 512 v-cols
  f32x4 acc[4][4] = {};
  for (int k0 = 0; k0 < Asz; k0 += 32) {
#pragma unroll
    for (int rep = 0; rep < 2; ++rep) {
      int seg = wave + rep * 4;
      int i = seg * 64 + lane;
      int r = i >> 2, c8 = (i & 3) * 8;
      long off = (long)(n0 + r) * Asz + k0 + c8;
      gld16(WT_hi + off, (char*)&b_hi[0][0] + seg * 1024);
      gld16(WT_lo + off, (char*)&b_lo[0][0] + seg * 1024);
    }
    Frag2 a[4];
#pragma unroll
    for (int m = 0; m < 4; ++m)
      a[m] = load_split8(AO + (m0 + wr * 64 + m * 16 + lr) * Asz + k0 + kg * 8);
    __syncthreads();   // drains vmcnt -> B tiles ready
    bh8 bh_[4], bl[4];
#pragma unroll
    for (int n = 0; n < 4; ++n) {
      bh_[n] = *(const bh8*)&b_hi[wc * 64 + n * 16 + lr][kg * 8];
      bl[n]  = *(const bh8*)&b_lo[wc * 64 + n * 16 + lr][kg * 8];
    }
#pragma unroll
    for (int m = 0; m < 4; ++m)
#pragma unroll
      for (int n = 0; n < 4; ++n) {
        acc[m][n] = __builtin_amdgcn_mfma_f32_16x16x32_bf16(a[m].hi, bh_[n], acc[m][n], 0, 0, 0);
        acc[m][n] = __builtin_amdgcn_mfma_f32_16x16x32_bf16(a[m].hi, bl[n],  acc[m][n], 0, 0, 0);
        acc[m][n] = __builtin_amdgcn_mfma_f32_16x16x32_bf16(a[m].lo, bh_[n], acc[m][n], 0, 0, 0);
      }
    __syncthreads();   // protect LDS reuse
  }
#pragma unroll
  for (int m = 0; m < 4; ++m)
#pragma unroll
    for (int n = 0; n < 4; ++n)
#pragma unroll
      for (int j = 0; j < 4; ++j) {
        float x = acc[m][n][j];
        unsigned int u = __float_as_uint(x);
        unsigned short h = (unsigned short)(u >> 16);
        float lof = x - __uint_as_float(u & 0xffff0000u);
        unsigned short l = (unsigned short)(__float_as_uint(lof) >> 16);
        long row = m0 + wr * 64 + m * 16 + kg * 4 + j;
        int  col = n0 + wc * 64 + n * 16 + lr;
        aM_hi[row * Asz + col] = h;
        aM_lo[row * Asz + col] = l;
      }
}

// sim tile (64 t-rows x 128 n) 3-term split MFMA; A direct-to-reg from inputs,
// B via global_load_lds from aM_hi/lo; +lin+bias, tanh, masked softmax -> attn bf16
__global__ __launch_bounds__(512) void sim_fused(
    const float* __restrict__ inputs, const unsigned short* __restrict__ aMh,
    const unsigned short* __restrict__ aMl, const float* __restrict__ lin_a,
    const float* __restrict__ lin_b, const int* __restrict__ mask,
    const float* __restrict__ bias, unsigned short* __restrict__ attn_bf)
{
  __shared__ union SU {
    struct { unsigned short b_hi[128][32], b_lo[128][32]; } st;
    float S[64][132];
  } u;
  int b = blockIdx.y;
  int t0 = blockIdx.x * 64;
  int tid = threadIdx.x;
  int wave = tid >> 6, lane = tid & 63;
  int wr = wave >> 2, wc = wave & 3;   // 2x4 wave grid: 32-row x 32-col per wave
  int lr = lane & 15, kg = lane >> 4;
  const float* Ap = inputs + ((long)b * Tsz + t0) * Vsz;
  const unsigned short* Bh = aMh + (long)b * Nsz * Vsz;
  const unsigned short* Bl = aMl + (long)b * Nsz * Vsz;
  f32x4 acc[2][2] = {};
  for (int k0 = 0; k0 < Vsz; k0 += 32) {
    {
      int i = wave * 64 + lane;        // 512 lane-loads per array
      int r = i >> 2, c8 = (i & 3) * 8;
      long off = (long)r * Vsz + k0 + c8;
      gld16(Bh + off, (char*)&u.st.b_hi[0][0] + wave * 1024);
      gld16(Bl + off, (char*)&u.st.b_lo[0][0] + wave * 1024);
    }
    Frag2 a[2];
#pragma unroll
    for (int m = 0; m < 2; ++m)
      a[m] = load_split8(Ap + (long)(wr * 32 + m * 16 + lr) * Vsz + k0 + kg * 8);
    __syncthreads();
    bh8 bh_[2], bl[2];
#pragma unroll
    for (int n = 0; n < 2; ++n) {
      bh_[n] = *(const bh8*)&u.st.b_hi[wc * 32 + n * 16 + lr][kg * 8];
      bl[n]  = *(const bh8*)&u.st.b_lo[wc * 32 + n * 16 + lr][kg * 8];
    }
#pragma unroll
    for (int m = 0; m < 2; ++m)
#pragma unroll
      for (int n = 0; n < 2; ++n) {
        acc[m][n] = __builtin_amdgcn_mfma_f32_16x16x32_bf16(a[m].hi, bh_[n], acc[m][n], 0, 0, 0);
        acc[m][n] = __builtin_amdgcn_mfma_f32_16x16x32_bf16(a[m].hi, bl[n],  acc[m][n], 0, 0, 0);
        acc[m][n] = __builtin_amdgcn_mfma_f32_16x16x32_bf16(a[m].lo, bh_[n], acc[m][n], 0, 0, 0);
      }
    __syncthreads();
  }
#pragma unroll
  for (int m = 0; m < 2; ++m)
#pragma unroll
    for (int n = 0; n < 2; ++n)
#pragma unroll
      for (int j = 0; j < 4; ++j)
        u.S[wr * 32 + m * 16 + kg * 4 + j][wc * 32 + n * 16 + lr] = acc[m][n][j];
  __syncthreads();

  float la0 = lin_a[b * Nsz + lane];
  float la1 = lin_a[b * Nsz + 64 + lane];
  int   mk0 = mask[b * Nsz + lane];
  int   mk1 = mask[b * Nsz + 64 + lane];
  float bs  = bias[0];
#pragma unroll
  for (int rr = 0; rr < 8; ++rr) {
    int r = wave * 8 + rr;
    int tI = t0 + r;
    float lb = lin_b[b * Tsz + tI] + bs;
    float s0 = u.S[r][lane] + la0 + lb;
    float s1 = u.S[r][64 + lane] + la1 + lb;
    s0 = fast_tanh(s0); s1 = fast_tanh(s1);
    float v0 = mk0 ? s0 : -1e30f;
    float v1 = mk1 ? s1 : -1e30f;
    float mx = fmaxf(v0, v1);
#pragma unroll
    for (int off = 32; off; off >>= 1) mx = fmaxf(mx, __shfl_xor(mx, off));
    float e0 = mk0 ? __expf(v0 - mx) : 0.f;
    float e1 = mk1 ? __expf(v1 - mx) : 0.f;
    float sm = e0 + e1;
#pragma unroll
    for (int off = 32; off; off >>= 1) sm += __shfl_xor(sm, off);
    float inv = 1.f / sm;
    long base = ((long)b * Tsz + tI) * Nsz;
    attn_bf[base + lane]      = f2bf(e0 * inv);
    attn_bf[base + 64 + lane] = f2bf(e1 * inv);
  }
}

// AO[b][n][a] f32 -> AOt[b][a][n] bf16 (XOR-swizzled LDS transpose)
__global__ __launch_bounds__(256) void ao_transpose(
    const float* __restrict__ AO, unsigned short* __restrict__ AOt)
{
  __shared__ unsigned short t[128][128];
  int b = blockIdx.x >> 2;
  int a0 = (blockIdx.x & 3) * 128;
  int tid = threadIdx.x;
#pragma unroll
  for (int l = 0; l < 16; ++l) {
    int idx = tid + l * 256;
    int r = idx >> 5, c = (idx & 31) * 4;      // r = n, c = a-local
    float4 v = *(const float4*)(AO + ((long)b * Nsz + r) * Asz + a0 + c);
    ushort4 h;
    unsigned short* hp = (unsigned short*)&h;
    hp[0] = f2bf(v.x); hp[1] = f2bf(v.y); hp[2] = f2bf(v.z); hp[3] = f2bf(v.w);
    int key = ((r >> 3) & 7) << 2;
    *(ushort4*)&t[r][c ^ key] = h;
  }
  __syncthreads();
#pragma unroll
  for (int l = 0; l < 8; ++l) {
    int idx = tid + l * 256;
    int ra = idx >> 4, cc = idx & 15;          // ra = a-local, cc = n-chunk
    int key = (cc & 7) << 2;
    union { unsigned short s[8]; uint4 q; } g;
#pragma unroll
    for (int j = 0; j < 8; ++j) g.s[j] = t[cc * 8 + j][ra ^ key];
    *(uint4*)&AOt[((long)b * Asz + a0 + ra) * Nsz + cc * 8] = g.q;
  }
}

// context = attn(bf16) @ AO via AOt; both operands via global_load_lds
__global__ __launch_bounds__(256) void gemm_ctx(
    const unsigned short* __restrict__ attn_bf, const unsigned short* __restrict__ AOt,
    float* __restrict__ out)
{
  __shared__ unsigned short a_t[128][32];
  __shared__ unsigned short b_t[128][32];
  int b = blockIdx.z;
  int m0 = blockIdx.x * 128, n0 = blockIdx.y * 128;
  int tid = threadIdx.x;
  int wave = tid >> 6, lane = tid & 63;
  int wr = wave >> 1, wc = wave & 1;
  int lr = lane & 15, kg = lane >> 4;
  const unsigned short* Ap = attn_bf + (long)b * Tsz * Nsz;
  const unsigned short* Bp = AOt + (long)b * Asz * Nsz;
  f32x4 acc[4][4] = {};
  for (int k0 = 0; k0 < Nsz; k0 += 32) {
#pragma unroll
    for (int rep = 0; rep < 2; ++rep) {
      int seg = wave + rep * 4;
      int i = seg * 64 + lane;
      int r = i >> 2, c8 = (i & 3) * 8;
      gld16(Ap + (long)(m0 + r) * Nsz + k0 + c8, (char*)&a_t[0][0] + seg * 1024);
      gld16(Bp + (long)(n0 + r) * Nsz + k0 + c8, (char*)&b_t[0][0] + seg * 1024);
    }
    __syncthreads();
    bh8 af[4], bf_[4];
#pragma unroll
    for (int m = 0; m < 4; ++m) af[m] = *(const bh8*)&a_t[wr * 64 + m * 16 + lr][kg * 8];
#pragma unroll
    for (int n = 0; n < 4; ++n) bf_[n] = *(const bh8*)&b_t[wc * 64 + n * 16 + lr][kg * 8];
#pragma unroll
    for (int m = 0; m < 4; ++m)
#pragma unroll
      for (int n = 0; n < 4; ++n)
        acc[m][n] = __builtin_amdgcn_mfma_f32_16x16x32_bf16(af[m], bf_[n], acc[m][n], 0, 0, 0);
    __syncthreads();
  }
#pragma unroll
  for (int m = 0; m < 4; ++m)
#pragma unroll
    for (int n = 0; n < 4; ++n)
#pragma unroll
      for (int j = 0; j < 4; ++j)
        out[((long)b * Tsz + m0 + wr * 64 + m * 16 + kg * 4 + j) * Asz + n0 + wc * 64 + n * 16 + lr]
          = acc[m][n][j];
}

extern "C" void kernel_launch(void* const* d_in, const int* in_sizes, int n_in,
                              void* d_out, int out_size, void* d_ws, size_t ws_size,
                              hipStream_t stream) {
  const float* inputs = (const float*)d_in[0];
  const float* AO     = (const float*)d_in[1];
  const int*   mask   = (const int*)d_in[2];
  const float* W      = (const float*)d_in[3];
  const float* a_w    = (const float*)d_in[4];
  const float* b_w    = (const float*)d_in[5];
  const float* bias   = (const float*)d_in[6];
  float* out = (float*)d_out;
  char* wsb  = (char*)d_ws;

  unsigned short* aM_hi   = (unsigned short*)wsb;                 // 16,777,216 B
  unsigned short* aM_lo   = (unsigned short*)(wsb + 16777216);    // 16,777,216 B
  unsigned short* AOt     = (unsigned short*)wsb;                 // overlaps aM_hi (after sim)
  unsigned short* WT_hi   = (unsigned short*)(wsb + 33554432);    // 524,288 B
  unsigned short* WT_lo   = (unsigned short*)(wsb + 34078720);    // 524,288 B
  float*          lin_a   = (float*)(wsb + 34603008);             // 65,536 B
  float*          lin_b   = (float*)(wsb + 34668544);             // 131,072 B
  unsigned short* attn_bf = (unsigned short*)(wsb + 34799616);    // 8,388,608 B -> ends 43.2 MB

  prep<<<LIN_BLOCKS + 64, 256, 0, stream>>>(AO, inputs, W, a_w, b_w, lin_a, lin_b, WT_hi, WT_lo);
  gemm_aM<<<dim3(128, 4), 256, 0, stream>>>(AO, WT_hi, WT_lo, aM_hi, aM_lo);
  sim_fused<<<dim3(4, 128), 512, 0, stream>>>(inputs, aM_hi, aM_lo, lin_a, lin_b, mask, bias, attn_bf);
  ao_transpose<<<512, 256, 0, stream>>>(AO, AOt);
  gemm_ctx<<<dim3(2, 4, 128), 256, 0, stream>>>(attn_bf, AOt, out);
}